// Round 9
// baseline (818.176 us; speedup 1.0000x reference)
//
#include <hip/hip_runtime.h>
#include <hip/hip_bf16.h>
#include <cstdint>

#define N_NODES 50000
#define N_EDGES 800000
#define DIM     128
#define NLAYERS 4

#define SCAN_BLK 256
#define NB ((N_NODES + SCAN_BLK - 1) / SCAN_BLK)   // 196 scan blocks

// ---------------- CSR build (two-pass: src-major bucket, then src-ordered
// emission into dst-major lists). Ascending-src order within each dst list
// gives all co-resident gin_layer blocks the same moving src window -> the
// gather becomes L2-resident instead of random beyond-L2 traffic. ----------

__global__ __launch_bounds__(256) void zero_kernel(int* __restrict__ p, int n) {
    int i = blockIdx.x * blockDim.x + threadIdx.x;
    if (i < n) p[i] = 0;
}

__global__ __launch_bounds__(256) void count_kernel(const int* __restrict__ key,
                                                    int* __restrict__ cnt) {
    int e = blockIdx.x * blockDim.x + threadIdx.x;
    if (e < N_EDGES) atomicAdd(&cnt[key[e]], 1);
}

// per-block exclusive scan of cnt -> off (partial), block totals -> bsum
__global__ __launch_bounds__(SCAN_BLK) void scanA(const int* __restrict__ cnt,
                                                  int* __restrict__ off,
                                                  int* __restrict__ bsum) {
    __shared__ int s[SCAN_BLK];
    const int t = threadIdx.x;
    const int i = blockIdx.x * SCAN_BLK + t;
    int v = (i < N_NODES) ? cnt[i] : 0;
    s[t] = v;
    __syncthreads();
    for (int d = 1; d < SCAN_BLK; d <<= 1) {
        int add = (t >= d) ? s[t - d] : 0;
        __syncthreads();
        s[t] += add;
        __syncthreads();
    }
    if (i < N_NODES) off[i] = s[t] - v;        // exclusive within block
    if (t == SCAN_BLK - 1) bsum[blockIdx.x] = s[t];
}

// exclusive scan of block sums in place (NB <= 256)
__global__ __launch_bounds__(SCAN_BLK) void scanB(int* __restrict__ bsum) {
    __shared__ int s[SCAN_BLK];
    const int t = threadIdx.x;
    int v = (t < NB) ? bsum[t] : 0;
    s[t] = v;
    __syncthreads();
    for (int d = 1; d < SCAN_BLK; d <<= 1) {
        int add = (t >= d) ? s[t - d] : 0;
        __syncthreads();
        s[t] += add;
        __syncthreads();
    }
    if (t < NB) bsum[t] = s[t] - v;            // exclusive
}

__global__ __launch_bounds__(SCAN_BLK) void scanC(int* __restrict__ off,
                                                  const int* __restrict__ bsum,
                                                  int* __restrict__ cur) {
    const int i = blockIdx.x * SCAN_BLK + threadIdx.x;
    if (i < N_NODES) {
        int o = off[i] + bsum[blockIdx.x];
        off[i] = o;
        cur[i] = o;
    }
    if (i == 0) off[N_NODES] = N_EDGES;
}

// pass 1: bucket edges by src (arbitrary order within a src)
__global__ __launch_bounds__(256) void bucket_src_kernel(const int* __restrict__ src,
                                                         const int* __restrict__ dst,
                                                         int* __restrict__ cur2,
                                                         int* __restrict__ csc_dst) {
    int e = blockIdx.x * blockDim.x + threadIdx.x;
    if (e < N_EDGES) {
        int s = src[e];
        int pos = atomicAdd(&cur2[s], 1);
        csc_dst[pos] = dst[e];
    }
}

// pass 2: walk srcs in ascending (thread-id) order, emit into dst lists ->
// each dst's list is ~ascending in src.
__global__ __launch_bounds__(256) void order_kernel(const int* __restrict__ off2,
                                                    const int* __restrict__ csc_dst,
                                                    int* __restrict__ cur,
                                                    int* __restrict__ csr) {
    int s = blockIdx.x * blockDim.x + threadIdx.x;
    if (s < N_NODES) {
        const int p0 = off2[s], p1 = off2[s + 1];
        for (int p = p0; p < p1; ++p) {
            int d = csc_dst[p];
            int pos = atomicAdd(&cur[d], 1);
            csr[pos] = s;
        }
    }
}

// ---------------- fused GIN layer: agg -> GEMM1+ReLU -> GEMM2 ----------------
// RT rows per block, 256 threads. Gather is float4-per-lane: a 32-lane group
// loads one full 512B row per instruction, 8 rows in flight per group.
// Neighbor lists are ~src-ascending: all co-resident blocks sweep the same
// src window together, so gathers hit L2.

#define RT 32
#define LDW 132    // padded row stride (floats)
#define MAXE 1024  // staged-index capacity (block avg ~512; >22 sigma headroom)

__global__ __launch_bounds__(256) void gin_layer(
    const float* __restrict__ xin, const int* __restrict__ off,
    const int* __restrict__ csr,
    const float* __restrict__ W1, const float* __restrict__ b1,
    const float* __restrict__ W2, const float* __restrict__ b2,
    float* __restrict__ xout)
{
    __shared__ float sA[RT][LDW];
    __shared__ int   sIdx[MAXE];
    __shared__ int   sOff[RT + 1];
    const int tid  = threadIdx.x;
    const int base = blockIdx.x * RT;
    const int rtop = min(RT, N_NODES - base);   // valid rows in this block

    if (tid <= rtop) sOff[tid] = off[base + tid];
    __syncthreads();

    const int e0 = sOff[0];
    const int nE = sOff[rtop] - e0;
    const bool staged = (nE <= MAXE);
    if (staged) {
        for (int i = tid; i < nE; i += 256) sIdx[i] = csr[e0 + i];
    }
    __syncthreads();

    // ---- phase 1: float4 aggregation into sA ----
    {
        const int c = tid & 31;          // float4 column: floats 4c..4c+3
        const int g = tid >> 5;          // row group 0..7
        const float4* xin4 = reinterpret_cast<const float4*>(xin);
        #pragma unroll
        for (int it = 0; it < 4; ++it) {
            const int rr = g + it * 8;
            if (rr < rtop) {
                const int node = base + rr;
                float4 a = xin4[node * 32 + c];   // self (eps=0)
                const int k0 = sOff[rr] - e0, k1 = sOff[rr + 1] - e0;
                int k = k0;
                if (staged) {
                    for (; k + 8 <= k1; k += 8) {
                        int id[8];
                        #pragma unroll
                        for (int j = 0; j < 8; ++j) id[j] = sIdx[k + j];
                        float4 v0 = xin4[id[0] * 32 + c];
                        float4 v1 = xin4[id[1] * 32 + c];
                        float4 v2 = xin4[id[2] * 32 + c];
                        float4 v3 = xin4[id[3] * 32 + c];
                        float4 v4 = xin4[id[4] * 32 + c];
                        float4 v5 = xin4[id[5] * 32 + c];
                        float4 v6 = xin4[id[6] * 32 + c];
                        float4 v7 = xin4[id[7] * 32 + c];
                        a.x += ((v0.x + v1.x) + (v2.x + v3.x)) + ((v4.x + v5.x) + (v6.x + v7.x));
                        a.y += ((v0.y + v1.y) + (v2.y + v3.y)) + ((v4.y + v5.y) + (v6.y + v7.y));
                        a.z += ((v0.z + v1.z) + (v2.z + v3.z)) + ((v4.z + v5.z) + (v6.z + v7.z));
                        a.w += ((v0.w + v1.w) + (v2.w + v3.w)) + ((v4.w + v5.w) + (v6.w + v7.w));
                    }
                    for (; k < k1; ++k) {
                        float4 v = xin4[sIdx[k] * 32 + c];
                        a.x += v.x; a.y += v.y; a.z += v.z; a.w += v.w;
                    }
                } else {
                    for (; k < k1; ++k) {
                        float4 v = xin4[csr[e0 + k] * 32 + c];
                        a.x += v.x; a.y += v.y; a.z += v.z; a.w += v.w;
                    }
                }
                *reinterpret_cast<float4*>(&sA[rr][c * 4]) = a;
            }
        }
    }
    __syncthreads();

    const int tc = tid & 31;   // col group: cols tc*4 .. tc*4+3
    const int tr = tid >> 5;   // row group: rows tr*4 .. tr*4+3

    // ---- phase 2: acc = relu(sA @ W1 + b1) (held in registers) ----
    float acc[4][4] = {};
    {
        const float4* Wv = reinterpret_cast<const float4*>(W1);
        #pragma unroll 4
        for (int k4 = 0; k4 < DIM / 4; ++k4) {
            float4 w[4];
            #pragma unroll
            for (int j = 0; j < 4; ++j) w[j] = Wv[(k4 * 4 + j) * 32 + tc];
            #pragma unroll
            for (int i = 0; i < 4; ++i) {
                const float4 a = *reinterpret_cast<const float4*>(&sA[tr * 4 + i][k4 * 4]);
                acc[i][0] += a.x * w[0].x + a.y * w[1].x + a.z * w[2].x + a.w * w[3].x;
                acc[i][1] += a.x * w[0].y + a.y * w[1].y + a.z * w[2].y + a.w * w[3].y;
                acc[i][2] += a.x * w[0].z + a.y * w[1].z + a.z * w[2].z + a.w * w[3].z;
                acc[i][3] += a.x * w[0].w + a.y * w[1].w + a.z * w[2].w + a.w * w[3].w;
            }
        }
        const float4 b = reinterpret_cast<const float4*>(b1)[tc];
        #pragma unroll
        for (int i = 0; i < 4; ++i) {
            acc[i][0] = fmaxf(acc[i][0] + b.x, 0.f);
            acc[i][1] = fmaxf(acc[i][1] + b.y, 0.f);
            acc[i][2] = fmaxf(acc[i][2] + b.z, 0.f);
            acc[i][3] = fmaxf(acc[i][3] + b.w, 0.f);
        }
    }
    __syncthreads();   // all reads of sA complete

    // write H back into sA (reuse)
    #pragma unroll
    for (int i = 0; i < 4; ++i) {
        float4 h;
        h.x = acc[i][0]; h.y = acc[i][1]; h.z = acc[i][2]; h.w = acc[i][3];
        *reinterpret_cast<float4*>(&sA[tr * 4 + i][tc * 4]) = h;
    }
    __syncthreads();

    // ---- phase 3: xout = sA(=H) @ W2 + b2 ----
    {
        float acc2[4][4] = {};
        const float4* Wv = reinterpret_cast<const float4*>(W2);
        #pragma unroll 4
        for (int k4 = 0; k4 < DIM / 4; ++k4) {
            float4 w[4];
            #pragma unroll
            for (int j = 0; j < 4; ++j) w[j] = Wv[(k4 * 4 + j) * 32 + tc];
            #pragma unroll
            for (int i = 0; i < 4; ++i) {
                const float4 a = *reinterpret_cast<const float4*>(&sA[tr * 4 + i][k4 * 4]);
                acc2[i][0] += a.x * w[0].x + a.y * w[1].x + a.z * w[2].x + a.w * w[3].x;
                acc2[i][1] += a.x * w[0].y + a.y * w[1].y + a.z * w[2].y + a.w * w[3].y;
                acc2[i][2] += a.x * w[0].z + a.y * w[1].z + a.z * w[2].z + a.w * w[3].z;
                acc2[i][3] += a.x * w[0].w + a.y * w[1].w + a.z * w[2].w + a.w * w[3].w;
            }
        }
        const float4 b = reinterpret_cast<const float4*>(b2)[tc];
        #pragma unroll
        for (int i = 0; i < 4; ++i) {
            const int node = base + tr * 4 + i;
            if (node < N_NODES) {
                float4 o;
                o.x = acc2[i][0] + b.x;
                o.y = acc2[i][1] + b.y;
                o.z = acc2[i][2] + b.z;
                o.w = acc2[i][3] + b.w;
                reinterpret_cast<float4*>(xout + node * DIM)[tc] = o;
            }
        }
    }
}

// ---------------- launch ----------------

extern "C" void kernel_launch(void* const* d_in, const int* in_sizes, int n_in,
                              void* d_out, int out_size, void* d_ws, size_t ws_size,
                              hipStream_t stream) {
    const float* x  = (const float*)d_in[0];
    const int*   ei = (const int*)d_in[1];     // [2][N_EDGES]: src row then dst row
    // d_in[2] = batch (unused)
    const float* W1 = (const float*)d_in[3];
    const float* b1 = (const float*)d_in[4];
    const float* W2 = (const float*)d_in[5];
    const float* b2 = (const float*)d_in[6];
    float* out = (float*)d_out;

    const int* src = ei;
    const int* dst = ei + N_EDGES;

    // workspace layout (d_out is the second ping-pong buffer). ≈ 33 MB.
    float* bufA    = (float*)d_ws;                          // N_NODES*DIM floats
    int*   cnt     = (int*)(bufA + (size_t)N_NODES * DIM);  // N (dst counts)
    int*   cnt2    = cnt + N_NODES;                         // N (src counts)
    int*   offs    = cnt2 + N_NODES;                        // N+1 (dst offsets)
    int*   off2    = offs + N_NODES + 1;                    // N+1 (src offsets)
    int*   cur     = off2 + N_NODES + 1;                    // N (dst cursors)
    int*   cur2    = cur + N_NODES;                         // N (src cursors)
    int*   bsum    = cur2 + N_NODES;                        // 256
    int*   bsum2   = bsum + 256;                            // 256
    int*   csr     = bsum2 + 256;                           // E (src-ordered, dst-major)
    int*   csc_dst = csr + N_EDGES;                         // E (dst per src-major slot)

    // --- build CSR with ~ascending-src lists, once per call ---
    zero_kernel<<<(2 * N_NODES + 255) / 256, 256, 0, stream>>>(cnt, 2 * N_NODES);
    count_kernel<<<(N_EDGES + 255) / 256, 256, 0, stream>>>(dst, cnt);
    count_kernel<<<(N_EDGES + 255) / 256, 256, 0, stream>>>(src, cnt2);
    scanA<<<NB, SCAN_BLK, 0, stream>>>(cnt, offs, bsum);
    scanB<<<1, SCAN_BLK, 0, stream>>>(bsum);
    scanC<<<NB, SCAN_BLK, 0, stream>>>(offs, bsum, cur);
    scanA<<<NB, SCAN_BLK, 0, stream>>>(cnt2, off2, bsum2);
    scanB<<<1, SCAN_BLK, 0, stream>>>(bsum2);
    scanC<<<NB, SCAN_BLK, 0, stream>>>(off2, bsum2, cur2);
    bucket_src_kernel<<<(N_EDGES + 255) / 256, 256, 0, stream>>>(src, dst, cur2, csc_dst);
    order_kernel<<<NB, 256, 0, stream>>>(off2, csc_dst, cur, csr);

    const int nblk = (N_NODES + RT - 1) / RT;
    // layer 0: x -> bufA
    gin_layer<<<nblk, 256, 0, stream>>>(x,    offs, csr, W1 + 0 * DIM * DIM, b1 + 0 * DIM,
                                        W2 + 0 * DIM * DIM, b2 + 0 * DIM, bufA);
    // layer 1: bufA -> out (d_out doubles as ping-pong buffer)
    gin_layer<<<nblk, 256, 0, stream>>>(bufA, offs, csr, W1 + 1 * DIM * DIM, b1 + 1 * DIM,
                                        W2 + 1 * DIM * DIM, b2 + 1 * DIM, out);
    // layer 2: out -> bufA
    gin_layer<<<nblk, 256, 0, stream>>>(out,  offs, csr, W1 + 2 * DIM * DIM, b1 + 2 * DIM,
                                        W2 + 2 * DIM * DIM, b2 + 2 * DIM, bufA);
    // layer 3: bufA -> out
    gin_layer<<<nblk, 256, 0, stream>>>(bufA, offs, csr, W1 + 3 * DIM * DIM, b1 + 3 * DIM,
                                        W2 + 3 * DIM * DIM, b2 + 3 * DIM, out);
}

// Round 10
// 677.230 us; speedup vs baseline: 1.2081x; 1.2081x over previous
//
#include <hip/hip_runtime.h>
#include <hip/hip_bf16.h>
#include <cstdint>

#define N_NODES 50000
#define N_EDGES 800000
#define DIM     128
#define NLAYERS 4

#define SCAN_BLK 256
#define NB ((N_NODES + SCAN_BLK - 1) / SCAN_BLK)   // 196 scan blocks

// ---------------- CSR build (single-pass; list order is irrelevant) --------

__global__ __launch_bounds__(256) void zero_kernel(int* __restrict__ p, int n) {
    int i = blockIdx.x * blockDim.x + threadIdx.x;
    if (i < n) p[i] = 0;
}

__global__ __launch_bounds__(256) void count_kernel(const int* __restrict__ key,
                                                    int* __restrict__ cnt) {
    int e = blockIdx.x * blockDim.x + threadIdx.x;
    if (e < N_EDGES) atomicAdd(&cnt[key[e]], 1);
}

__global__ __launch_bounds__(SCAN_BLK) void scanA(const int* __restrict__ cnt,
                                                  int* __restrict__ off,
                                                  int* __restrict__ bsum) {
    __shared__ int s[SCAN_BLK];
    const int t = threadIdx.x;
    const int i = blockIdx.x * SCAN_BLK + t;
    int v = (i < N_NODES) ? cnt[i] : 0;
    s[t] = v;
    __syncthreads();
    for (int d = 1; d < SCAN_BLK; d <<= 1) {
        int add = (t >= d) ? s[t - d] : 0;
        __syncthreads();
        s[t] += add;
        __syncthreads();
    }
    if (i < N_NODES) off[i] = s[t] - v;
    if (t == SCAN_BLK - 1) bsum[blockIdx.x] = s[t];
}

__global__ __launch_bounds__(SCAN_BLK) void scanB(int* __restrict__ bsum) {
    __shared__ int s[SCAN_BLK];
    const int t = threadIdx.x;
    int v = (t < NB) ? bsum[t] : 0;
    s[t] = v;
    __syncthreads();
    for (int d = 1; d < SCAN_BLK; d <<= 1) {
        int add = (t >= d) ? s[t - d] : 0;
        __syncthreads();
        s[t] += add;
        __syncthreads();
    }
    if (t < NB) bsum[t] = s[t] - v;
}

__global__ __launch_bounds__(SCAN_BLK) void scanC(int* __restrict__ off,
                                                  const int* __restrict__ bsum,
                                                  int* __restrict__ cur) {
    const int i = blockIdx.x * SCAN_BLK + threadIdx.x;
    if (i < N_NODES) {
        int o = off[i] + bsum[blockIdx.x];
        off[i] = o;
        cur[i] = o;
    }
    if (i == 0) off[N_NODES] = N_EDGES;
}

__global__ __launch_bounds__(256) void scatter_kernel(const int* __restrict__ src,
                                                      const int* __restrict__ dst,
                                                      int* __restrict__ cur,
                                                      int* __restrict__ csr) {
    int e = blockIdx.x * blockDim.x + threadIdx.x;
    if (e < N_EDGES) {
        int d = dst[e];
        int pos = atomicAdd(&cur[d], 1);
        csr[pos] = src[e];
    }
}

// ---------------- bf16 helpers ----------------

static __device__ __forceinline__ float bf2f(unsigned short u) {
    unsigned v = (unsigned)u << 16;
    float f;
    __builtin_memcpy(&f, &v, 4);
    return f;
}
static __device__ __forceinline__ unsigned short f2bf(float f) {
    __hip_bfloat16 h = __float2bfloat16(f);   // RNE
    unsigned short u;
    __builtin_memcpy(&u, &h, 2);
    return u;
}

// x (fp32) -> xh (bf16 shadow table), used once for layer 0's input
__global__ __launch_bounds__(256) void conv_kernel(const float* __restrict__ x,
                                                   unsigned short* __restrict__ xh) {
    int i = blockIdx.x * blockDim.x + threadIdx.x;   // float4 index
    const int n4 = N_NODES * DIM / 4;
    if (i < n4) {
        float4 v = reinterpret_cast<const float4*>(x)[i];
        ushort4 h;
        h.x = f2bf(v.x); h.y = f2bf(v.y); h.z = f2bf(v.z); h.w = f2bf(v.w);
        reinterpret_cast<ushort4*>(xh)[i] = h;
    }
}

// ---------------- fused GIN layer: agg -> GEMM1+ReLU -> GEMM2 ----------------
// Neighbor rows are gathered from the bf16 shadow table (256B/row): halves
// the compulsory per-XCD L2 fill (beyond-L2 wall ~1.3 TB/s, R7/R9 evidence).
// Self-term and all arithmetic stay fp32. Each layer emits fp32 out + bf16
// shadow for the next layer.

#define RT 32
#define LDW 132    // padded row stride (floats)
#define MAXE 1024  // staged-index capacity (block avg ~512)

__global__ __launch_bounds__(256) void gin_layer(
    const float* __restrict__ xin,           // fp32 input (self term)
    const unsigned short* __restrict__ xh,   // bf16 shadow of xin (gather)
    const int* __restrict__ off,
    const int* __restrict__ csr,
    const float* __restrict__ W1, const float* __restrict__ b1,
    const float* __restrict__ W2, const float* __restrict__ b2,
    float* __restrict__ xout,                // fp32 output
    unsigned short* __restrict__ xhout)      // bf16 shadow of output
{
    __shared__ float sA[RT][LDW];
    __shared__ int   sIdx[MAXE];
    __shared__ int   sOff[RT + 1];
    const int tid  = threadIdx.x;
    const int base = blockIdx.x * RT;
    const int rtop = min(RT, N_NODES - base);

    if (tid <= rtop) sOff[tid] = off[base + tid];
    __syncthreads();

    const int e0 = sOff[0];
    const int nE = sOff[rtop] - e0;
    const bool staged = (nE <= MAXE);
    if (staged) {
        for (int i = tid; i < nE; i += 256) sIdx[i] = csr[e0 + i];
    }
    __syncthreads();

    // ---- phase 1: bf16 gather + fp32 self into sA ----
    {
        const int c = tid & 31;          // ushort4 column: elems 4c..4c+3
        const int g = tid >> 5;          // row group 0..7
        const float4*  xin4 = reinterpret_cast<const float4*>(xin);
        const ushort4* xh4  = reinterpret_cast<const ushort4*>(xh);
        #pragma unroll
        for (int it = 0; it < 4; ++it) {
            const int rr = g + it * 8;
            if (rr < rtop) {
                const int node = base + rr;
                float4 a = xin4[node * 32 + c];   // self term, fp32
                const int k0 = sOff[rr] - e0, k1 = sOff[rr + 1] - e0;
                int k = k0;
                if (staged) {
                    for (; k + 8 <= k1; k += 8) {
                        int id[8];
                        #pragma unroll
                        for (int j = 0; j < 8; ++j) id[j] = sIdx[k + j];
                        ushort4 u0 = xh4[id[0] * 32 + c];
                        ushort4 u1 = xh4[id[1] * 32 + c];
                        ushort4 u2 = xh4[id[2] * 32 + c];
                        ushort4 u3 = xh4[id[3] * 32 + c];
                        ushort4 u4 = xh4[id[4] * 32 + c];
                        ushort4 u5 = xh4[id[5] * 32 + c];
                        ushort4 u6 = xh4[id[6] * 32 + c];
                        ushort4 u7 = xh4[id[7] * 32 + c];
                        a.x += ((bf2f(u0.x) + bf2f(u1.x)) + (bf2f(u2.x) + bf2f(u3.x))) +
                               ((bf2f(u4.x) + bf2f(u5.x)) + (bf2f(u6.x) + bf2f(u7.x)));
                        a.y += ((bf2f(u0.y) + bf2f(u1.y)) + (bf2f(u2.y) + bf2f(u3.y))) +
                               ((bf2f(u4.y) + bf2f(u5.y)) + (bf2f(u6.y) + bf2f(u7.y)));
                        a.z += ((bf2f(u0.z) + bf2f(u1.z)) + (bf2f(u2.z) + bf2f(u3.z))) +
                               ((bf2f(u4.z) + bf2f(u5.z)) + (bf2f(u6.z) + bf2f(u7.z)));
                        a.w += ((bf2f(u0.w) + bf2f(u1.w)) + (bf2f(u2.w) + bf2f(u3.w))) +
                               ((bf2f(u4.w) + bf2f(u5.w)) + (bf2f(u6.w) + bf2f(u7.w)));
                    }
                    for (; k < k1; ++k) {
                        ushort4 u = xh4[sIdx[k] * 32 + c];
                        a.x += bf2f(u.x); a.y += bf2f(u.y);
                        a.z += bf2f(u.z); a.w += bf2f(u.w);
                    }
                } else {
                    for (; k < k1; ++k) {
                        ushort4 u = xh4[csr[e0 + k] * 32 + c];
                        a.x += bf2f(u.x); a.y += bf2f(u.y);
                        a.z += bf2f(u.z); a.w += bf2f(u.w);
                    }
                }
                *reinterpret_cast<float4*>(&sA[rr][c * 4]) = a;
            }
        }
    }
    __syncthreads();

    const int tc = tid & 31;
    const int tr = tid >> 5;

    // ---- phase 2: acc = relu(sA @ W1 + b1) (registers) ----
    float acc[4][4] = {};
    {
        const float4* Wv = reinterpret_cast<const float4*>(W1);
        #pragma unroll 4
        for (int k4 = 0; k4 < DIM / 4; ++k4) {
            float4 w[4];
            #pragma unroll
            for (int j = 0; j < 4; ++j) w[j] = Wv[(k4 * 4 + j) * 32 + tc];
            #pragma unroll
            for (int i = 0; i < 4; ++i) {
                const float4 a = *reinterpret_cast<const float4*>(&sA[tr * 4 + i][k4 * 4]);
                acc[i][0] += a.x * w[0].x + a.y * w[1].x + a.z * w[2].x + a.w * w[3].x;
                acc[i][1] += a.x * w[0].y + a.y * w[1].y + a.z * w[2].y + a.w * w[3].y;
                acc[i][2] += a.x * w[0].z + a.y * w[1].z + a.z * w[2].z + a.w * w[3].z;
                acc[i][3] += a.x * w[0].w + a.y * w[1].w + a.z * w[2].w + a.w * w[3].w;
            }
        }
        const float4 b = reinterpret_cast<const float4*>(b1)[tc];
        #pragma unroll
        for (int i = 0; i < 4; ++i) {
            acc[i][0] = fmaxf(acc[i][0] + b.x, 0.f);
            acc[i][1] = fmaxf(acc[i][1] + b.y, 0.f);
            acc[i][2] = fmaxf(acc[i][2] + b.z, 0.f);
            acc[i][3] = fmaxf(acc[i][3] + b.w, 0.f);
        }
    }
    __syncthreads();

    // write H back into sA (reuse)
    #pragma unroll
    for (int i = 0; i < 4; ++i) {
        float4 h;
        h.x = acc[i][0]; h.y = acc[i][1]; h.z = acc[i][2]; h.w = acc[i][3];
        *reinterpret_cast<float4*>(&sA[tr * 4 + i][tc * 4]) = h;
    }
    __syncthreads();

    // ---- phase 3: xout = sA(=H) @ W2 + b2, plus bf16 shadow ----
    {
        float acc2[4][4] = {};
        const float4* Wv = reinterpret_cast<const float4*>(W2);
        #pragma unroll 4
        for (int k4 = 0; k4 < DIM / 4; ++k4) {
            float4 w[4];
            #pragma unroll
            for (int j = 0; j < 4; ++j) w[j] = Wv[(k4 * 4 + j) * 32 + tc];
            #pragma unroll
            for (int i = 0; i < 4; ++i) {
                const float4 a = *reinterpret_cast<const float4*>(&sA[tr * 4 + i][k4 * 4]);
                acc2[i][0] += a.x * w[0].x + a.y * w[1].x + a.z * w[2].x + a.w * w[3].x;
                acc2[i][1] += a.x * w[0].y + a.y * w[1].y + a.z * w[2].y + a.w * w[3].y;
                acc2[i][2] += a.x * w[0].z + a.y * w[1].z + a.z * w[2].z + a.w * w[3].z;
                acc2[i][3] += a.x * w[0].w + a.y * w[1].w + a.z * w[2].w + a.w * w[3].w;
            }
        }
        const float4 b = reinterpret_cast<const float4*>(b2)[tc];
        #pragma unroll
        for (int i = 0; i < 4; ++i) {
            const int node = base + tr * 4 + i;
            if (node < N_NODES) {
                float4 o;
                o.x = acc2[i][0] + b.x;
                o.y = acc2[i][1] + b.y;
                o.z = acc2[i][2] + b.z;
                o.w = acc2[i][3] + b.w;
                reinterpret_cast<float4*>(xout + node * DIM)[tc] = o;
                ushort4 h;
                h.x = f2bf(o.x); h.y = f2bf(o.y); h.z = f2bf(o.z); h.w = f2bf(o.w);
                reinterpret_cast<ushort4*>(xhout + node * DIM)[tc] = h;
            }
        }
    }
}

// ---------------- launch ----------------

extern "C" void kernel_launch(void* const* d_in, const int* in_sizes, int n_in,
                              void* d_out, int out_size, void* d_ws, size_t ws_size,
                              hipStream_t stream) {
    const float* x  = (const float*)d_in[0];
    const int*   ei = (const int*)d_in[1];     // [2][N_EDGES]: src row then dst row
    // d_in[2] = batch (unused)
    const float* W1 = (const float*)d_in[3];
    const float* b1 = (const float*)d_in[4];
    const float* W2 = (const float*)d_in[5];
    const float* b2 = (const float*)d_in[6];
    float* out = (float*)d_out;

    const int* src = ei;
    const int* dst = ei + N_EDGES;

    // workspace: fp32 ping buffer (d_out is the pong), two bf16 shadows,
    // then CSR arrays. ≈ 25.6 + 12.8 + 12.8 + 3.6 MB ≈ 55 MB.
    float*          bufA = (float*)d_ws;                            // N*DIM f32
    unsigned short* xhA  = (unsigned short*)(bufA + (size_t)N_NODES * DIM); // N*DIM u16
    unsigned short* xhB  = xhA + (size_t)N_NODES * DIM;             // N*DIM u16
    int*   cnt  = (int*)(xhB + (size_t)N_NODES * DIM);              // N
    int*   offs = cnt + N_NODES;                                    // N+1
    int*   cur  = offs + N_NODES + 1;                               // N
    int*   bsum = cur + N_NODES;                                    // 256
    int*   csr  = bsum + 256;                                       // E

    // --- build CSR (dst -> srcs), single-pass (order irrelevant: R9) ---
    zero_kernel<<<NB, 256, 0, stream>>>(cnt, N_NODES);
    count_kernel<<<(N_EDGES + 255) / 256, 256, 0, stream>>>(dst, cnt);
    scanA<<<NB, SCAN_BLK, 0, stream>>>(cnt, offs, bsum);
    scanB<<<1, SCAN_BLK, 0, stream>>>(bsum);
    scanC<<<NB, SCAN_BLK, 0, stream>>>(offs, bsum, cur);
    scatter_kernel<<<(N_EDGES + 255) / 256, 256, 0, stream>>>(src, dst, cur, csr);

    // bf16 shadow of the initial x
    conv_kernel<<<(N_NODES * DIM / 4 + 255) / 256, 256, 0, stream>>>(x, xhA);

    const int nblk = (N_NODES + RT - 1) / RT;
    // layer 0: (x, xhA) -> (bufA, xhB)
    gin_layer<<<nblk, 256, 0, stream>>>(x, xhA, offs, csr,
                                        W1 + 0 * DIM * DIM, b1 + 0 * DIM,
                                        W2 + 0 * DIM * DIM, b2 + 0 * DIM, bufA, xhB);
    // layer 1: (bufA, xhB) -> (out, xhA)
    gin_layer<<<nblk, 256, 0, stream>>>(bufA, xhB, offs, csr,
                                        W1 + 1 * DIM * DIM, b1 + 1 * DIM,
                                        W2 + 1 * DIM * DIM, b2 + 1 * DIM, out, xhA);
    // layer 2: (out, xhA) -> (bufA, xhB)
    gin_layer<<<nblk, 256, 0, stream>>>(out, xhA, offs, csr,
                                        W1 + 2 * DIM * DIM, b1 + 2 * DIM,
                                        W2 + 2 * DIM * DIM, b2 + 2 * DIM, bufA, xhB);
    // layer 3: (bufA, xhB) -> (out, xhA)  (final shadow write unused)
    gin_layer<<<nblk, 256, 0, stream>>>(bufA, xhB, offs, csr,
                                        W1 + 3 * DIM * DIM, b1 + 3 * DIM,
                                        W2 + 3 * DIM * DIM, b2 + 3 * DIM, out, xhA);
}

// Round 11
// 634.113 us; speedup vs baseline: 1.2903x; 1.0680x over previous
//
#include <hip/hip_runtime.h>
#include <hip/hip_bf16.h>
#include <cstdint>

#define N_NODES 50000
#define N_EDGES 800000
#define DIM     128
#define NLAYERS 4

#define SCAN_BLK 256
#define NB ((N_NODES + SCAN_BLK - 1) / SCAN_BLK)   // 196 scan blocks

// ---------------- CSR build (single-pass) ----------------

__global__ __launch_bounds__(256) void zero_kernel(int* __restrict__ p, int n) {
    int i = blockIdx.x * blockDim.x + threadIdx.x;
    if (i < n) p[i] = 0;
}

__global__ __launch_bounds__(256) void count_kernel(const int* __restrict__ key,
                                                    int* __restrict__ cnt) {
    int e = blockIdx.x * blockDim.x + threadIdx.x;
    if (e < N_EDGES) atomicAdd(&cnt[key[e]], 1);
}

__global__ __launch_bounds__(SCAN_BLK) void scanA(const int* __restrict__ cnt,
                                                  int* __restrict__ off,
                                                  int* __restrict__ bsum) {
    __shared__ int s[SCAN_BLK];
    const int t = threadIdx.x;
    const int i = blockIdx.x * SCAN_BLK + t;
    int v = (i < N_NODES) ? cnt[i] : 0;
    s[t] = v;
    __syncthreads();
    for (int d = 1; d < SCAN_BLK; d <<= 1) {
        int add = (t >= d) ? s[t - d] : 0;
        __syncthreads();
        s[t] += add;
        __syncthreads();
    }
    if (i < N_NODES) off[i] = s[t] - v;
    if (t == SCAN_BLK - 1) bsum[blockIdx.x] = s[t];
}

__global__ __launch_bounds__(SCAN_BLK) void scanB(int* __restrict__ bsum) {
    __shared__ int s[SCAN_BLK];
    const int t = threadIdx.x;
    int v = (t < NB) ? bsum[t] : 0;
    s[t] = v;
    __syncthreads();
    for (int d = 1; d < SCAN_BLK; d <<= 1) {
        int add = (t >= d) ? s[t - d] : 0;
        __syncthreads();
        s[t] += add;
        __syncthreads();
    }
    if (t < NB) bsum[t] = s[t] - v;
}

__global__ __launch_bounds__(SCAN_BLK) void scanC(int* __restrict__ off,
                                                  const int* __restrict__ bsum,
                                                  int* __restrict__ cur) {
    const int i = blockIdx.x * SCAN_BLK + threadIdx.x;
    if (i < N_NODES) {
        int o = off[i] + bsum[blockIdx.x];
        off[i] = o;
        cur[i] = o;
    }
    if (i == 0) off[N_NODES] = N_EDGES;
}

__global__ __launch_bounds__(256) void scatter_kernel(const int* __restrict__ src,
                                                      const int* __restrict__ dst,
                                                      int* __restrict__ cur,
                                                      int* __restrict__ csr) {
    int e = blockIdx.x * blockDim.x + threadIdx.x;
    if (e < N_EDGES) {
        int d = dst[e];
        int pos = atomicAdd(&cur[d], 1);
        csr[pos] = src[e];
    }
}

// ---------------- bf16 helpers ----------------

static __device__ __forceinline__ float bf2f(unsigned short u) {
    unsigned v = (unsigned)u << 16;
    float f;
    __builtin_memcpy(&f, &v, 4);
    return f;
}
static __device__ __forceinline__ unsigned short f2bf(float f) {
    __hip_bfloat16 h = __float2bfloat16(f);   // RNE
    unsigned short u;
    __builtin_memcpy(&u, &h, 2);
    return u;
}

__global__ __launch_bounds__(256) void conv_kernel(const float* __restrict__ x,
                                                   unsigned short* __restrict__ xh) {
    int i = blockIdx.x * blockDim.x + threadIdx.x;   // float4 index
    const int n4 = N_NODES * DIM / 4;
    if (i < n4) {
        float4 v = reinterpret_cast<const float4*>(x)[i];
        ushort4 h;
        h.x = f2bf(v.x); h.y = f2bf(v.y); h.z = f2bf(v.z); h.w = f2bf(v.w);
        reinterpret_cast<ushort4*>(xh)[i] = h;
    }
}

// ---------------- agg kernel: node-per-group deep-ILP gather ----------------
// One 32-lane group per node, no LDS -> max wave residency. All (up to) 32
// neighbor-row loads issued before any accumulate: 8 KB in flight per group,
// ~100+ KB per CU, to cover the ~600cy mixed L2/HBM latency (R10 post-mortem:
// exposed gather latency, not bandwidth, is the bottleneck).

__global__ __launch_bounds__(256) void agg_kernel(
    const float* __restrict__ xin,          // fp32 input (self term)
    const unsigned short* __restrict__ xh,  // bf16 shadow (gather source)
    const int* __restrict__ off,
    const int* __restrict__ csr,
    float* __restrict__ agg)                // fp32 aggregated output
{
    const int tid  = threadIdx.x;
    const int c    = tid & 31;              // ushort4 column (elems 4c..4c+3)
    const int node = blockIdx.x * 8 + (tid >> 5);
    if (node >= N_NODES) return;

    const float4*  xin4 = reinterpret_cast<const float4*>(xin);
    const ushort4* xh4  = reinterpret_cast<const ushort4*>(xh);

    const int k0 = off[node], k1 = off[node + 1];
    float4 a = xin4[node * 32 + c];          // self (eps=0), fp32

    for (int kb = k0; kb < k1; kb += 32) {
        const int m = min(32, k1 - kb);
        int idxv = (c < m) ? csr[kb + c] : 0;   // coalesced index load
        ushort4 v[16], v2[16];
        // issue ALL gathers first (up to 32 in flight)
        #pragma unroll
        for (int j = 0; j < 16; ++j) {
            int id = __shfl(idxv, j, 32);
            if (j < m) v[j] = xh4[id * 32 + c];
        }
        #pragma unroll
        for (int j = 0; j < 16; ++j) {
            int id = __shfl(idxv, j + 16, 32);
            if (j + 16 < m) v2[j] = xh4[id * 32 + c];
        }
        // then accumulate
        #pragma unroll
        for (int j = 0; j < 16; ++j) {
            if (j < m) {
                a.x += bf2f(v[j].x); a.y += bf2f(v[j].y);
                a.z += bf2f(v[j].z); a.w += bf2f(v[j].w);
            }
        }
        #pragma unroll
        for (int j = 0; j < 16; ++j) {
            if (j + 16 < m) {
                a.x += bf2f(v2[j].x); a.y += bf2f(v2[j].y);
                a.z += bf2f(v2[j].z); a.w += bf2f(v2[j].w);
            }
        }
    }
    reinterpret_cast<float4*>(agg)[node * 32 + c] = a;
}

// ---------------- mlp kernel: GEMM1+ReLU -> GEMM2 ----------------
// Reads its 32 agg rows (coalesced) into LDS, so in-place agg==xout is safe.

#define RT 32
#define LDW 132    // padded row stride (floats)

__global__ __launch_bounds__(256) void mlp_kernel(
    const float* __restrict__ agg,
    const float* __restrict__ W1, const float* __restrict__ b1,
    const float* __restrict__ W2, const float* __restrict__ b2,
    float* __restrict__ xout,
    unsigned short* __restrict__ xhout)
{
    __shared__ float sA[RT][LDW];
    const int tid  = threadIdx.x;
    const int base = blockIdx.x * RT;

    // ---- stage agg rows into sA (coalesced float4) ----
    {
        const float4* agg4 = reinterpret_cast<const float4*>(agg);
        for (int i = tid; i < RT * 32; i += 256) {
            const int r = i >> 5, cc = i & 31;
            if (base + r < N_NODES) {
                *reinterpret_cast<float4*>(&sA[r][cc * 4]) = agg4[(base + r) * 32 + cc];
            }
        }
    }
    __syncthreads();

    const int tc = tid & 31;
    const int tr = tid >> 5;

    // ---- GEMM1: acc = relu(sA @ W1 + b1) ----
    float acc[4][4] = {};
    {
        const float4* Wv = reinterpret_cast<const float4*>(W1);
        #pragma unroll 4
        for (int k4 = 0; k4 < DIM / 4; ++k4) {
            float4 w[4];
            #pragma unroll
            for (int j = 0; j < 4; ++j) w[j] = Wv[(k4 * 4 + j) * 32 + tc];
            #pragma unroll
            for (int i = 0; i < 4; ++i) {
                const float4 a = *reinterpret_cast<const float4*>(&sA[tr * 4 + i][k4 * 4]);
                acc[i][0] += a.x * w[0].x + a.y * w[1].x + a.z * w[2].x + a.w * w[3].x;
                acc[i][1] += a.x * w[0].y + a.y * w[1].y + a.z * w[2].y + a.w * w[3].y;
                acc[i][2] += a.x * w[0].z + a.y * w[1].z + a.z * w[2].z + a.w * w[3].z;
                acc[i][3] += a.x * w[0].w + a.y * w[1].w + a.z * w[2].w + a.w * w[3].w;
            }
        }
        const float4 b = reinterpret_cast<const float4*>(b1)[tc];
        #pragma unroll
        for (int i = 0; i < 4; ++i) {
            acc[i][0] = fmaxf(acc[i][0] + b.x, 0.f);
            acc[i][1] = fmaxf(acc[i][1] + b.y, 0.f);
            acc[i][2] = fmaxf(acc[i][2] + b.z, 0.f);
            acc[i][3] = fmaxf(acc[i][3] + b.w, 0.f);
        }
    }
    __syncthreads();

    // write H back into sA (reuse)
    #pragma unroll
    for (int i = 0; i < 4; ++i) {
        float4 h;
        h.x = acc[i][0]; h.y = acc[i][1]; h.z = acc[i][2]; h.w = acc[i][3];
        *reinterpret_cast<float4*>(&sA[tr * 4 + i][tc * 4]) = h;
    }
    __syncthreads();

    // ---- GEMM2: xout = sA(=H) @ W2 + b2, plus bf16 shadow ----
    {
        float acc2[4][4] = {};
        const float4* Wv = reinterpret_cast<const float4*>(W2);
        #pragma unroll 4
        for (int k4 = 0; k4 < DIM / 4; ++k4) {
            float4 w[4];
            #pragma unroll
            for (int j = 0; j < 4; ++j) w[j] = Wv[(k4 * 4 + j) * 32 + tc];
            #pragma unroll
            for (int i = 0; i < 4; ++i) {
                const float4 a = *reinterpret_cast<const float4*>(&sA[tr * 4 + i][k4 * 4]);
                acc2[i][0] += a.x * w[0].x + a.y * w[1].x + a.z * w[2].x + a.w * w[3].x;
                acc2[i][1] += a.x * w[0].y + a.y * w[1].y + a.z * w[2].y + a.w * w[3].y;
                acc2[i][2] += a.x * w[0].z + a.y * w[1].z + a.z * w[2].z + a.w * w[3].z;
                acc2[i][3] += a.x * w[0].w + a.y * w[1].w + a.z * w[2].w + a.w * w[3].w;
            }
        }
        const float4 b = reinterpret_cast<const float4*>(b2)[tc];
        #pragma unroll
        for (int i = 0; i < 4; ++i) {
            const int node = base + tr * 4 + i;
            if (node < N_NODES) {
                float4 o;
                o.x = acc2[i][0] + b.x;
                o.y = acc2[i][1] + b.y;
                o.z = acc2[i][2] + b.z;
                o.w = acc2[i][3] + b.w;
                reinterpret_cast<float4*>(xout + node * DIM)[tc] = o;
                ushort4 h;
                h.x = f2bf(o.x); h.y = f2bf(o.y); h.z = f2bf(o.z); h.w = f2bf(o.w);
                reinterpret_cast<ushort4*>(xhout + node * DIM)[tc] = h;
            }
        }
    }
}

// ---------------- launch ----------------

extern "C" void kernel_launch(void* const* d_in, const int* in_sizes, int n_in,
                              void* d_out, int out_size, void* d_ws, size_t ws_size,
                              hipStream_t stream) {
    const float* x  = (const float*)d_in[0];
    const int*   ei = (const int*)d_in[1];     // [2][N_EDGES]: src row then dst row
    // d_in[2] = batch (unused)
    const float* W1 = (const float*)d_in[3];
    const float* b1 = (const float*)d_in[4];
    const float* W2 = (const float*)d_in[5];
    const float* b2 = (const float*)d_in[6];
    float* out = (float*)d_out;

    const int* src = ei;
    const int* dst = ei + N_EDGES;

    // workspace: fp32 ping buffer, two bf16 shadows, CSR arrays (≈55 MB).
    // d_out doubles as the agg buffer G every layer (row-local, in-place-safe).
    float*          bufA = (float*)d_ws;                                    // N*DIM f32
    unsigned short* xhA  = (unsigned short*)(bufA + (size_t)N_NODES * DIM); // N*DIM u16
    unsigned short* xhB  = xhA + (size_t)N_NODES * DIM;                     // N*DIM u16
    int*   cnt  = (int*)(xhB + (size_t)N_NODES * DIM);                      // N
    int*   offs = cnt + N_NODES;                                            // N+1
    int*   cur  = offs + N_NODES + 1;                                       // N
    int*   bsum = cur + N_NODES;                                            // 256
    int*   csr  = bsum + 256;                                               // E
    float* G    = out;                                                      // agg buffer

    // --- build CSR (dst -> srcs) ---
    zero_kernel<<<NB, 256, 0, stream>>>(cnt, N_NODES);
    count_kernel<<<(N_EDGES + 255) / 256, 256, 0, stream>>>(dst, cnt);
    scanA<<<NB, SCAN_BLK, 0, stream>>>(cnt, offs, bsum);
    scanB<<<1, SCAN_BLK, 0, stream>>>(bsum);
    scanC<<<NB, SCAN_BLK, 0, stream>>>(offs, bsum, cur);
    scatter_kernel<<<(N_EDGES + 255) / 256, 256, 0, stream>>>(src, dst, cur, csr);

    // bf16 shadow of the initial x
    conv_kernel<<<(N_NODES * DIM / 4 + 255) / 256, 256, 0, stream>>>(x, xhA);

    const int nblk_agg = (N_NODES + 7) / 8;          // 1 node per 32-lane group
    const int nblk_mlp = (N_NODES + RT - 1) / RT;

    // layer 0: AGG(x, xhA) -> G ; MLP(G) -> (bufA, xhB)
    agg_kernel<<<nblk_agg, 256, 0, stream>>>(x, xhA, offs, csr, G);
    mlp_kernel<<<nblk_mlp, 256, 0, stream>>>(G, W1 + 0 * DIM * DIM, b1 + 0 * DIM,
                                             W2 + 0 * DIM * DIM, b2 + 0 * DIM, bufA, xhB);
    // layer 1
    agg_kernel<<<nblk_agg, 256, 0, stream>>>(bufA, xhB, offs, csr, G);
    mlp_kernel<<<nblk_mlp, 256, 0, stream>>>(G, W1 + 1 * DIM * DIM, b1 + 1 * DIM,
                                             W2 + 1 * DIM * DIM, b2 + 1 * DIM, bufA, xhA);
    // layer 2
    agg_kernel<<<nblk_agg, 256, 0, stream>>>(bufA, xhA, offs, csr, G);
    mlp_kernel<<<nblk_mlp, 256, 0, stream>>>(G, W1 + 2 * DIM * DIM, b1 + 2 * DIM,
                                             W2 + 2 * DIM * DIM, b2 + 2 * DIM, bufA, xhB);
    // layer 3: MLP writes d_out in place over G (each block stages its own
    // rows into LDS before overwriting them; agg is row-local)
    agg_kernel<<<nblk_agg, 256, 0, stream>>>(bufA, xhB, offs, csr, G);
    mlp_kernel<<<nblk_mlp, 256, 0, stream>>>(G, W1 + 3 * DIM * DIM, b1 + 3 * DIM,
                                             W2 + 3 * DIM * DIM, b2 + 3 * DIM, out, xhA);
}